// Round 7
// baseline (138.434 us; speedup 1.0000x reference)
//
#include <hip/hip_runtime.h>

typedef __attribute__((ext_vector_type(4))) float f32x4;
typedef __attribute__((ext_vector_type(4))) int   i32x4;
typedef __attribute__((ext_vector_type(8))) int   i32x8;

#define DIM 256
#define D4  64    // float4 per row

// One wave per row. Rows [0,N): exact fp32 pos_sim -> posPart[row] + normalized
// pk -> fp8 e4m3 (plain byte-k order). Rows [N,N+M): normalized nv -> fp8.
__global__ __launch_bounds__(256) void normalize_kernel(
    const float4* __restrict__ pk, const float4* __restrict__ pv,
    const float4* __restrict__ nv, unsigned int* __restrict__ pkn,
    unsigned int* __restrict__ nvn, float* __restrict__ posPart, int N) {
  int row  = blockIdx.x * 4 + (threadIdx.x >> 6);
  int lane = threadIdx.x & 63;
  if (row < N) {
    float4 x = pk[row * D4 + lane];
    float4 y = pv[row * D4 + lane];
    float skk = x.x*x.x + x.y*x.y + x.z*x.z + x.w*x.w;
    float svv = y.x*y.x + y.y*y.y + y.z*y.z + y.w*y.w;
    float skv = x.x*y.x + x.y*y.y + x.z*y.z + x.w*y.w;
#pragma unroll
    for (int m = 32; m >= 1; m >>= 1) {
      skk += __shfl_xor(skk, m, 64);
      svv += __shfl_xor(svv, m, 64);
      skv += __shfl_xor(skv, m, 64);
    }
    float nk  = fmaxf(sqrtf(skk), 1e-8f);
    float nvv = fmaxf(sqrtf(svv), 1e-8f);
    if (lane == 0) posPart[row] = skv / (nk * nvv);
    float rk = 1.0f / nk;
    int w = __builtin_amdgcn_cvt_pk_fp8_f32(x.x * rk, x.y * rk, 0, false);
    w = __builtin_amdgcn_cvt_pk_fp8_f32(x.z * rk, x.w * rk, w, true);
    pkn[(size_t)row * 64 + lane] = (unsigned int)w;
  } else {
    int r2 = row - N;
    float4 x = nv[r2 * D4 + lane];
    float s = x.x*x.x + x.y*x.y + x.z*x.z + x.w*x.w;
#pragma unroll
    for (int m = 32; m >= 1; m >>= 1) s += __shfl_xor(s, m, 64);
    float rn = 1.0f / fmaxf(sqrtf(s), 1e-8f);
    int w = __builtin_amdgcn_cvt_pk_fp8_f32(x.x * rn, x.y * rn, 0, false);
    w = __builtin_amdgcn_cvt_pk_fp8_f32(x.z * rn, x.w * rn, w, true);
    nvn[(size_t)r2 * 64 + lane] = (unsigned int)w;
  }
}

// Fused fp8 GEMM (MX 16x16x128, unit scales = exact fp8) + exp(sim/2) + row-sum.
// R7: NO LDS, NO barriers. R5/R6's 3 __syncthreads each forced s_waitcnt
// vmcnt(0), phase-locking the 3 resident WGs into serialized stage->drain->MFMA
// (~42us, 3x the L2-traffic floor). Both fp8 matrices total 4MB = L2-resident,
// so each wave loads its MFMA frags DIRECTLY global->VGPR: lane (l15,q) reads
// contiguous 32B at row(l15)*256 + kb*128 + q*32 (16 rows x 128B segments per
// wave, zero overfetch, bytes land exactly in the verified MX frag order).
// 32 independent 16B loads issue up-front; compiler interleaves MFMA with
// fine-grained vmcnt(N) — the hipBLASLt-style pipeline the barrier forbade.
// WG 256 thr = 4 waves (2x2 of 64x64), tile 128x128, grid (M/128, N/128).
__global__ __launch_bounds__(256, 2) void gemm_lse_kernel(
    const unsigned char* __restrict__ gA, const unsigned char* __restrict__ gB,
    float* __restrict__ partial, int N) {
  const int tid  = threadIdx.x;
  const int lane = tid & 63;
  const int wv   = tid >> 6;
  const int wm   = wv >> 1, wn = wv & 1;
  const int l15  = lane & 15, q = lane >> 4;
  const int row0 = blockIdx.y * 128 + wm * 64;
  const int col0 = blockIdx.x * 128 + wn * 64;
  const float kLog2eHalf = 0.72134752044448170f;  // log2(e)/2
  const int kUnitScale = 0x7F7F7F7F;              // e8m0 127 = 2^0 per byte

  const unsigned char* pa = gA + (size_t)(row0 + l15) * 256 + q * 32;
  const unsigned char* pb = gB + (size_t)(col0 + l15) * 256 + q * 32;

  // ---- issue all frag loads (2 K-halves x 4 frags x lo/hi 16B, A and B) ----
  i32x4 alo[2][4], ahi[2][4], blo[2][4], bhi[2][4];
#pragma unroll
  for (int kb = 0; kb < 2; kb++)
#pragma unroll
    for (int i = 0; i < 4; i++) {
      alo[kb][i] = *(const i32x4*)(pa + i * 4096 + kb * 128);
      ahi[kb][i] = *(const i32x4*)(pa + i * 4096 + kb * 128 + 16);
      blo[kb][i] = *(const i32x4*)(pb + i * 4096 + kb * 128);
      bhi[kb][i] = *(const i32x4*)(pb + i * 4096 + kb * 128 + 16);
    }

  f32x4 acc[4][4];
#pragma unroll
  for (int mi = 0; mi < 4; mi++)
#pragma unroll
    for (int ni = 0; ni < 4; ni++) acc[mi][ni] = (f32x4){0.f, 0.f, 0.f, 0.f};

#pragma unroll
  for (int kb = 0; kb < 2; kb++) {
    i32x8 bf[4];
#pragma unroll
    for (int ni = 0; ni < 4; ni++)
      bf[ni] = (i32x8){blo[kb][ni].x, blo[kb][ni].y, blo[kb][ni].z, blo[kb][ni].w,
                       bhi[kb][ni].x, bhi[kb][ni].y, bhi[kb][ni].z, bhi[kb][ni].w};
#pragma unroll
    for (int mi = 0; mi < 4; mi++) {
      i32x8 af = (i32x8){alo[kb][mi].x, alo[kb][mi].y, alo[kb][mi].z, alo[kb][mi].w,
                         ahi[kb][mi].x, ahi[kb][mi].y, ahi[kb][mi].z, ahi[kb][mi].w};
#pragma unroll
      for (int ni = 0; ni < 4; ni++)
        acc[mi][ni] = __builtin_amdgcn_mfma_scale_f32_16x16x128_f8f6f4(
            af, bf[ni], acc[mi][ni],
            0, 0,                      // cbsz/blgp = fp8 e4m3
            0, kUnitScale, 0, kUnitScale);
    }
  }

  // epilogue: exp2(sim*log2e/2); butterfly over the 16 lane-cols; one dense
  // coalesced 256B store per wave, no atomics.
  // C/D layout (verified R2-R6): col = lane&15, row = quad*4 + rr.
  float keep = 0.f;
#pragma unroll
  for (int mi = 0; mi < 4; mi++)
#pragma unroll
    for (int rr = 0; rr < 4; rr++) {
      float v = 0.f;
#pragma unroll
      for (int ni = 0; ni < 4; ni++)
        v += __builtin_amdgcn_exp2f(acc[mi][ni][rr] * kLog2eHalf);
      v += __shfl_xor(v, 1, 16);
      v += __shfl_xor(v, 2, 16);
      v += __shfl_xor(v, 4, 16);
      v += __shfl_xor(v, 8, 16);
      if (l15 == mi * 4 + rr) keep = v;
    }
  int lrow = (l15 >> 2) * 16 + q * 4 + (l15 & 3);
  partial[(size_t)(blockIdx.x * 2 + wn) * N + (row0 - wm * 64) + wm * 64 + lrow] = keep;
}

// out = mean(ln(sum_j partial[j][row])) - 0.5*mean(posPart).
// 128 blocks, 4 slab-groups x 64 rows per block, unroll-8, LDS cross-group
// reduce (R6: ~3us, working — unchanged).
__global__ __launch_bounds__(256) void finalize_kernel(
    const float* __restrict__ partial, const float* __restrict__ posPart,
    float* __restrict__ out, int N, int slabsPerGroup, float invN) {
  __shared__ float red[4][64];
  int t  = threadIdx.x;
  int rl = t & 63, g = t >> 6;
  int row = blockIdx.x * 64 + rl;
  const float* p = partial + (size_t)(g * slabsPerGroup) * N + row;
  float s = 0.f;
#pragma unroll 8
  for (int j = 0; j < slabsPerGroup; j++) s += p[(size_t)j * N];
  red[g][rl] = s;
  __syncthreads();
  if (t < 64) {
    float tot = red[0][rl] + red[1][rl] + red[2][rl] + red[3][rl];
    float v = __builtin_amdgcn_logf(tot) * 0.69314718055994531f
              - 0.5f * posPart[row];
#pragma unroll
    for (int m = 32; m >= 1; m >>= 1) v += __shfl_xor(v, m, 64);
    if (rl == 0) atomicAdd(out, v * invN);
  }
}

extern "C" void kernel_launch(void* const* d_in, const int* in_sizes, int n_in,
                              void* d_out, int out_size, void* d_ws, size_t ws_size,
                              hipStream_t stream) {
  const float* pk = (const float*)d_in[0];
  const float* pv = (const float*)d_in[1];
  const float* nv = (const float*)d_in[2];
  int N = in_sizes[0] / DIM;   // 8192
  int M = in_sizes[2] / DIM;   // 8192
  float* out = (float*)d_out;

  unsigned char* pkn = (unsigned char*)d_ws;                   // [N,256] fp8
  unsigned char* nvn = pkn + (size_t)N * DIM;                  // [M,256] fp8
  float* partial = (float*)(nvn + (size_t)M * DIM);            // [M/64][N] fp32
  float* posPart = partial + (size_t)(M / 64) * N;             // [N] fp32

  hipMemsetAsync(out, 0, sizeof(float), stream);

  normalize_kernel<<<(N + M) / 4, 256, 0, stream>>>(
      (const float4*)pk, (const float4*)pv, (const float4*)nv,
      (unsigned int*)pkn, (unsigned int*)nvn, posPart, N);

  gemm_lse_kernel<<<dim3(M / 128, N / 128), 256, 0, stream>>>(
      pkn, nvn, partial, N);

  finalize_kernel<<<N / 64, 256, 0, stream>>>(
      partial, posPart, out, N, (M / 64) / 4, 1.0f / (float)N);
}

// Round 8
// 110.317 us; speedup vs baseline: 1.2549x; 1.2549x over previous
//
#include <hip/hip_runtime.h>

typedef __attribute__((ext_vector_type(4))) float f32x4;
typedef __attribute__((ext_vector_type(4))) int   i32x4;
typedef __attribute__((ext_vector_type(8))) int   i32x8;

#define DIM 256
#define D4  64    // float4 per row

// async global->LDS, 16B per lane; LDS dest = wave-uniform base + lane*16.
#define GLD_LDS16(g, l) __builtin_amdgcn_global_load_lds(                      \
    (const __attribute__((address_space(1))) void*)(g),                        \
    (__attribute__((address_space(3))) void*)(l), 16, 0, 0)

// One wave per row. Rows [0,N): exact fp32 pos_sim -> posPart[row] + normalized
// pk -> fp8 e4m3 (plain byte-k order). Rows [N,N+M): normalized nv -> fp8.
__global__ __launch_bounds__(256) void normalize_kernel(
    const float4* __restrict__ pk, const float4* __restrict__ pv,
    const float4* __restrict__ nv, unsigned int* __restrict__ pkn,
    unsigned int* __restrict__ nvn, float* __restrict__ posPart, int N) {
  int row  = blockIdx.x * 4 + (threadIdx.x >> 6);
  int lane = threadIdx.x & 63;
  if (row < N) {
    float4 x = pk[row * D4 + lane];
    float4 y = pv[row * D4 + lane];
    float skk = x.x*x.x + x.y*x.y + x.z*x.z + x.w*x.w;
    float svv = y.x*y.x + y.y*y.y + y.z*y.z + y.w*y.w;
    float skv = x.x*y.x + x.y*y.y + x.z*y.z + x.w*y.w;
#pragma unroll
    for (int m = 32; m >= 1; m >>= 1) {
      skk += __shfl_xor(skk, m, 64);
      svv += __shfl_xor(svv, m, 64);
      skv += __shfl_xor(skv, m, 64);
    }
    float nk  = fmaxf(sqrtf(skk), 1e-8f);
    float nvv = fmaxf(sqrtf(svv), 1e-8f);
    if (lane == 0) posPart[row] = skv / (nk * nvv);
    float rk = 1.0f / nk;
    int w = __builtin_amdgcn_cvt_pk_fp8_f32(x.x * rk, x.y * rk, 0, false);
    w = __builtin_amdgcn_cvt_pk_fp8_f32(x.z * rk, x.w * rk, w, true);
    pkn[(size_t)row * 64 + lane] = (unsigned int)w;
  } else {
    int r2 = row - N;
    float4 x = nv[r2 * D4 + lane];
    float s = x.x*x.x + x.y*x.y + x.z*x.z + x.w*x.w;
#pragma unroll
    for (int m = 32; m >= 1; m >>= 1) s += __shfl_xor(s, m, 64);
    float rn = 1.0f / fmaxf(sqrtf(s), 1e-8f);
    int w = __builtin_amdgcn_cvt_pk_fp8_f32(x.x * rn, x.y * rn, 0, false);
    w = __builtin_amdgcn_cvt_pk_fp8_f32(x.z * rn, x.w * rn, w, true);
    nvn[(size_t)r2 * 64 + lane] = (unsigned int)w;
  }
}

// Fused fp8 GEMM (MX 16x16x128, unit scales = exact fp8) + exp(sim/2) + row-sum.
// R8: persistent row-stripe WG with cross-tile double-buffered B staging.
//  - Every prior round exposed the staging drain: loads were issued right
//    before the barrier that vmcnt(0)-drains them. Now stage(t+1) is issued
//    BEFORE tile t's MFMA work, so the end-of-tile barrier drains loads that
//    had ~1100 cyc to complete -> drain ~ free (cp.async-style pipeline).
//  - A frags for the WG's 128-row stripe load ONCE global->VGPR (64 VGPRs,
//    R7-verified byte order) and are reused across all 8 col tiles.
//  - B staging/frag-read uses R4's XOR-16 swizzle (measured 0 conflicts).
// WG 256 thr = 4 waves (2x2 of 64x64), tile 128x128, 8 tiles/WG,
// grid (8 colgroups, 64 stripes) = 512 WGs = 2/CU (LDS 64KB/WG).
__global__ __launch_bounds__(256, 2) void gemm_lse_kernel(
    const unsigned char* __restrict__ gA, const unsigned char* __restrict__ gB,
    float* __restrict__ partial, int N) {
  __shared__ unsigned char Bs[2][32768];   // [buf][128 rows][256B swizzled]

  const int tid  = threadIdx.x;
  const int lane = tid & 63;
  const int wv   = tid >> 6;
  const int wm   = wv >> 1, wn = wv & 1;
  const int l15  = lane & 15, q = lane >> 4;
  const int row0 = blockIdx.y * 128;
  const int ct0  = blockIdx.x * 8;         // first col tile of this WG
  const float kLog2eHalf = 0.72134752044448170f;  // log2(e)/2
  const int kUnitScale = 0x7F7F7F7F;              // e8m0 127 = 2^0 per byte

  // ---- A frags: direct global->VGPR, once (R7 byte order, verified) ----
  const unsigned char* pa = gA + (size_t)(row0 + wm * 64 + l15) * 256 + q * 32;
  i32x4 alo[2][4], ahi[2][4];
#pragma unroll
  for (int kb = 0; kb < 2; kb++)
#pragma unroll
    for (int mi = 0; mi < 4; mi++) {
      alo[kb][mi] = *(const i32x4*)(pa + mi * 4096 + kb * 128);
      ahi[kb][mi] = *(const i32x4*)(pa + mi * 4096 + kb * 128 + 16);
    }

  // ---- stage B tile 0 ----
  {
    const unsigned char* pb = gB + (size_t)(ct0 * 128) * 256;
#pragma unroll
    for (int i = 0; i < 8; i++) {
      int c  = i * 256 + tid;            // chunk 0..2047
      int r  = c >> 4;
      int sc = ((c & 15) ^ (r & 15)) << 4;
      GLD_LDS16(pb + (size_t)r * 256 + sc, &Bs[0][c * 16]);
    }
  }
  __syncthreads();

  for (int ct = 0; ct < 8; ct++) {
    // ---- issue stage of B(t+1) into the other buffer (drained by the
    //      barrier at the END of this iteration, ~1100 cyc from now) ----
    if (ct < 7) {
      const unsigned char* pb = gB + (size_t)((ct0 + ct + 1) * 128) * 256;
      unsigned char* dst = Bs[(ct + 1) & 1];
#pragma unroll
      for (int i = 0; i < 8; i++) {
        int c  = i * 256 + tid;
        int r  = c >> 4;
        int sc = ((c & 15) ^ (r & 15)) << 4;
        GLD_LDS16(pb + (size_t)r * 256 + sc, dst + c * 16);
      }
    }

    // ---- compute tile ct from Bs[ct&1] ----
    const unsigned char* bs = Bs[ct & 1];
    f32x4 acc[4][4];
#pragma unroll
    for (int mi = 0; mi < 4; mi++)
#pragma unroll
      for (int ni = 0; ni < 4; ni++) acc[mi][ni] = (f32x4){0.f, 0.f, 0.f, 0.f};

#pragma unroll
    for (int kb = 0; kb < 2; kb++) {
      i32x8 bf[4];
#pragma unroll
      for (int ni = 0; ni < 4; ni++) {
        int r  = wn * 64 + ni * 16 + l15;
        int c0 = (kb * 8 + q * 2)     ^ (r & 15);
        int c1 = (kb * 8 + q * 2 + 1) ^ (r & 15);
        i32x4 lo = *(const i32x4*)(bs + r * 256 + c0 * 16);
        i32x4 hi = *(const i32x4*)(bs + r * 256 + c1 * 16);
        bf[ni] = (i32x8){lo.x, lo.y, lo.z, lo.w, hi.x, hi.y, hi.z, hi.w};
      }
#pragma unroll
      for (int mi = 0; mi < 4; mi++) {
        i32x8 af = (i32x8){alo[kb][mi].x, alo[kb][mi].y, alo[kb][mi].z, alo[kb][mi].w,
                           ahi[kb][mi].x, ahi[kb][mi].y, ahi[kb][mi].z, ahi[kb][mi].w};
#pragma unroll
        for (int ni = 0; ni < 4; ni++)
          acc[mi][ni] = __builtin_amdgcn_mfma_scale_f32_16x16x128_f8f6f4(
              af, bf[ni], acc[mi][ni],
              0, 0,                      // cbsz/blgp = fp8 e4m3
              0, kUnitScale, 0, kUnitScale);
      }
    }

    // epilogue: exp2(sim*log2e/2); butterfly over 16 lane-cols; one dense
    // coalesced 256B store per wave, no atomics.
    // C/D layout (verified R2-R7): col = lane&15, row = quad*4 + rr.
    float keep = 0.f;
#pragma unroll
    for (int mi = 0; mi < 4; mi++)
#pragma unroll
      for (int rr = 0; rr < 4; rr++) {
        float v = 0.f;
#pragma unroll
        for (int ni = 0; ni < 4; ni++)
          v += __builtin_amdgcn_exp2f(acc[mi][ni][rr] * kLog2eHalf);
        v += __shfl_xor(v, 1, 16);
        v += __shfl_xor(v, 2, 16);
        v += __shfl_xor(v, 4, 16);
        v += __shfl_xor(v, 8, 16);
        if (l15 == mi * 4 + rr) keep = v;
      }
    int lrow = (l15 >> 2) * 16 + q * 4 + (l15 & 3);
    partial[(size_t)((ct0 + ct) * 2 + wn) * N + row0 + wm * 64 + lrow] = keep;

    __syncthreads();   // drains stage(t+1) (already complete) + frag reads
  }
}

// out = mean(ln(sum_j partial[j][row])) - 0.5*mean(posPart).
// 128 blocks, 4 slab-groups x 64 rows per block, unroll-8, LDS cross-group
// reduce (R6: ~3us, working — unchanged).
__global__ __launch_bounds__(256) void finalize_kernel(
    const float* __restrict__ partial, const float* __restrict__ posPart,
    float* __restrict__ out, int N, int slabsPerGroup, float invN) {
  __shared__ float red[4][64];
  int t  = threadIdx.x;
  int rl = t & 63, g = t >> 6;
  int row = blockIdx.x * 64 + rl;
  const float* p = partial + (size_t)(g * slabsPerGroup) * N + row;
  float s = 0.f;
#pragma unroll 8
  for (int j = 0; j < slabsPerGroup; j++) s += p[(size_t)j * N];
  red[g][rl] = s;
  __syncthreads();
  if (t < 64) {
    float tot = red[0][rl] + red[1][rl] + red[2][rl] + red[3][rl];
    float v = __builtin_amdgcn_logf(tot) * 0.69314718055994531f
              - 0.5f * posPart[row];
#pragma unroll
    for (int m = 32; m >= 1; m >>= 1) v += __shfl_xor(v, m, 64);
    if (rl == 0) atomicAdd(out, v * invN);
  }
}

extern "C" void kernel_launch(void* const* d_in, const int* in_sizes, int n_in,
                              void* d_out, int out_size, void* d_ws, size_t ws_size,
                              hipStream_t stream) {
  const float* pk = (const float*)d_in[0];
  const float* pv = (const float*)d_in[1];
  const float* nv = (const float*)d_in[2];
  int N = in_sizes[0] / DIM;   // 8192
  int M = in_sizes[2] / DIM;   // 8192
  float* out = (float*)d_out;

  unsigned char* pkn = (unsigned char*)d_ws;                   // [N,256] fp8
  unsigned char* nvn = pkn + (size_t)N * DIM;                  // [M,256] fp8
  float* partial = (float*)(nvn + (size_t)M * DIM);            // [M/64][N] fp32
  float* posPart = partial + (size_t)(M / 64) * N;             // [N] fp32

  hipMemsetAsync(out, 0, sizeof(float), stream);

  normalize_kernel<<<(N + M) / 4, 256, 0, stream>>>(
      (const float4*)pk, (const float4*)pv, (const float4*)nv,
      (unsigned int*)pkn, (unsigned int*)nvn, posPart, N);

  gemm_lse_kernel<<<dim3(M / (128 * 8), N / 128), 256, 0, stream>>>(
      pkn, nvn, partial, N);

  finalize_kernel<<<N / 64, 256, 0, stream>>>(
      partial, posPart, out, N, (M / 64) / 4, 1.0f / (float)N);
}